// Round 4
// baseline (340.184 us; speedup 1.0000x reference)
//
#include <hip/hip_runtime.h>
#include <hip/hip_bf16.h>

#define NEG_SLOPE 0.2f

typedef __attribute__((ext_vector_type(8))) short bf16x8;
typedef __attribute__((ext_vector_type(4))) float f32x4;

__device__ __forceinline__ void gload_lds16(const void* g, void* l) {
    __builtin_amdgcn_global_load_lds((const __attribute__((address_space(1))) void*)g,
                                     (__attribute__((address_space(3))) void*)l,
                                     16, 0, 0);
}
__device__ __forceinline__ float bflo(unsigned int u) {
    return __uint_as_float(u << 16);
}
__device__ __forceinline__ float bfhi(unsigned int u) {
    return __uint_as_float(u & 0xffff0000u);
}
__device__ __forceinline__ unsigned short f2bf(float f) {
    __hip_bfloat16 h = __float2bfloat16(f);
    return *reinterpret_cast<unsigned short*>(&h);
}

// ---------------- CSR build ----------------

__global__ void k_hist(const int* __restrict__ ei, int E, int* counts) {
    int i = blockIdx.x * blockDim.x + threadIdx.x;
    if (i < E) atomicAdd(&counts[ei[E + i]], 1);
}

// chunked scan over (counts[i]+1) -> rowptr[0..n]; +1 = self loop
__global__ __launch_bounds__(1024) void k_scan(const int* __restrict__ counts,
                                               int* __restrict__ rowptr, int n) {
    __shared__ int wsum[16];
    __shared__ int wpre[16];
    int t = threadIdx.x;
    int chunk = (n + 1023) >> 10;
    int lo = t * chunk, hi = min(lo + chunk, n);
    if (lo > n) lo = n;
    if (hi < lo) hi = lo;
    int s = 0;
    for (int i = lo; i < hi; ++i) s += counts[i] + 1;
    int lane = t & 63, w = t >> 6;
    int v = s;
#pragma unroll
    for (int off = 1; off < 64; off <<= 1) {
        int u = __shfl_up(v, off);
        if (lane >= off) v += u;
    }
    if (lane == 63) wsum[w] = v;
    __syncthreads();
    if (w == 0 && lane < 16) {
        int x = wsum[lane];
#pragma unroll
        for (int off = 1; off < 16; off <<= 1) {
            int u = __shfl_up(x, off);
            if (lane >= off) x += u;
        }
        wpre[lane] = x - wsum[lane];
    }
    __syncthreads();
    int run = wpre[w] + v - s;
    for (int i = lo; i < hi; ++i) { rowptr[i] = run; run += counts[i] + 1; }
    if (t == 1023) rowptr[n] = run;
}

// self loop at slot rowptr[d]; edges at rowptr[d]+1+cursor
__global__ void k_scatter(const int* __restrict__ ei, int E, int n,
                          const int* __restrict__ rowptr, int* __restrict__ cursor,
                          int* __restrict__ csrc) {
    int i = blockIdx.x * blockDim.x + threadIdx.x;
    int tot = E + n;
    if (i >= tot) return;
    if (i >= E) {
        int d = i - E;
        csrc[rowptr[d]] = d;
    } else {
        int s = ei[i], d = ei[E + i];
        int pos = rowptr[d] + 1 + atomicAdd(&cursor[d], 1);
        csrc[pos] = s;
    }
}

// ---------------- fused conversions: xb pad-cast + 3 weight transposes ----------------

__global__ void k_prep(const float* __restrict__ x, const float* __restrict__ W0,
                       const float* __restrict__ W1, const float* __restrict__ W2,
                       __hip_bfloat16* __restrict__ xb, __hip_bfloat16* __restrict__ W0t,
                       __hip_bfloat16* __restrict__ W1t, __hip_bfloat16* __restrict__ W2t,
                       int N, int K0, int totA) {
    int i = blockIdx.x * blockDim.x + threadIdx.x;
    if (i < totA) {
        int r = i / K0;
        xb[i] = __float2bfloat16(r < N ? x[i] : 0.f);
        return;
    }
    i -= totA;
    if (i < K0 * 256) {
        int c = i / K0, k = i - c * K0;
        W0t[i] = __float2bfloat16(W0[k * 256 + c]);
        return;
    }
    i -= K0 * 256;
    if (i < 65536) {
        int c = i >> 8, k = i & 255;
        W1t[i] = __float2bfloat16(W1[k * 256 + c]);
        return;
    }
    i -= 65536;
    if (i < 65536) {
        int c = i >> 8, k = i & 255;
        W2t[i] = __float2bfloat16(W2[k * 256 + c]);
    }
}

// ---- bf16 MFMA GEMM + fused attn-coef epilogue ----
// C[Mpad,256] = A[Mpad,K] @ Bt[256,K]^T ; als/ald accumulated via f32 atomics.

__global__ __launch_bounds__(256) void k_gemm_mfma(
    const __hip_bfloat16* __restrict__ A,   // [Mpad][K]
    const __hip_bfloat16* __restrict__ Bt,  // [NC][K]
    __hip_bfloat16* __restrict__ Cb,        // [Mpad][NC]
    int K, int NC,
    const float* __restrict__ as_,          // [256] flattened (8 heads x 32)
    const float* __restrict__ ad_,
    float* __restrict__ als,                // [N][8], pre-zeroed
    float* __restrict__ ald, int N)
{
    __shared__ __hip_bfloat16 As[128 * 32];
    __shared__ __hip_bfloat16 Bs[128 * 32];
    int tid = threadIdx.x;
    int lane = tid & 63, w = tid >> 6;
    int wm = w >> 1, wn = w & 1;
    int rr = lane & 15, kg = lane >> 4;
    int bm = blockIdx.x * 128, bn = blockIdx.y * 128;

    f32x4 acc[4][4] = {};

    for (int k0 = 0; k0 < K; k0 += 32) {
#pragma unroll
        for (int s = 0; s < 2; ++s) {
            int c = tid + s * 256;
            int r = c >> 2, sl = c & 3;
            int ksrc = k0 + 8 * (sl ^ ((r >> 1) & 3));
            char* dstA = ((char*)As) + s * 4096 + w * 1024;
            char* dstB = ((char*)Bs) + s * 4096 + w * 1024;
            gload_lds16(A + (size_t)(bm + r) * K + ksrc, dstA);
            gload_lds16(Bt + (size_t)(bn + r) * K + ksrc, dstB);
        }
        __syncthreads();
        bf16x8 af[4], bfr[4];
#pragma unroll
        for (int i = 0; i < 4; ++i) {
            int row = wm * 64 + i * 16 + rr;
            af[i] = *(const bf16x8*)((const char*)As + row * 64 + ((kg ^ ((row >> 1) & 3)) << 4));
        }
#pragma unroll
        for (int j = 0; j < 4; ++j) {
            int col = wn * 64 + j * 16 + rr;
            bfr[j] = *(const bf16x8*)((const char*)Bs + col * 64 + ((kg ^ ((col >> 1) & 3)) << 4));
        }
#pragma unroll
        for (int i = 0; i < 4; ++i)
#pragma unroll
            for (int j = 0; j < 4; ++j)
                acc[i][j] = __builtin_amdgcn_mfma_f32_16x16x32_bf16(af[i], bfr[j], acc[i][j], 0, 0, 0);
        __syncthreads();
    }
    // store C (bf16)
#pragma unroll
    for (int i = 0; i < 4; ++i) {
#pragma unroll
        for (int j = 0; j < 4; ++j) {
            int col = bn + wn * 64 + j * 16 + rr;
#pragma unroll
            for (int q = 0; q < 4; ++q) {
                int row = bm + wm * 64 + i * 16 + kg * 4 + q;
                Cb[(size_t)row * NC + col] = __float2bfloat16(acc[i][j][q]);
            }
        }
    }
    // fused attention coefficients: als[row][h] = sum_{c in head h} xl[row][c]*as[c]
    int cbase = bn + wn * 64;     // 64 global cols per wave = 2 heads
    int hbase = cbase >> 5;
    float asv[4], adv[4];
#pragma unroll
    for (int j = 0; j < 4; ++j) {
        asv[j] = as_[cbase + j * 16 + rr];
        adv[j] = ad_[cbase + j * 16 + rr];
    }
#pragma unroll
    for (int i = 0; i < 4; ++i) {
#pragma unroll
        for (int hh = 0; hh < 2; ++hh) {
#pragma unroll
            for (int q = 0; q < 4; ++q) {
                float ps = acc[i][2 * hh][q] * asv[2 * hh] + acc[i][2 * hh + 1][q] * asv[2 * hh + 1];
                float pd = acc[i][2 * hh][q] * adv[2 * hh] + acc[i][2 * hh + 1][q] * adv[2 * hh + 1];
#pragma unroll
                for (int off = 1; off < 16; off <<= 1) {
                    ps += __shfl_xor(ps, off);
                    pd += __shfl_xor(pd, off);
                }
                int row = bm + wm * 64 + i * 16 + kg * 4 + q;
                if (rr == 0 && row < N) {
                    atomicAdd(&als[row * 8 + hbase + hh], ps);
                    atomicAdd(&ald[row * 8 + hbase + hh], pd);
                }
            }
        }
    }
}

// ---------------- pipelined single-pass flash aggregation + ELU (+ optional matvec) ----
// stats mapping: lane = 8*slot + head ; gather mapping: half = lane>>5, 8 ch/lane
// pair TT covers edge base + half + 2*TT.

#define FMA8(XV, AL)                                              \
    {                                                             \
        acc[0] += (AL) * bflo(XV.x); acc[1] += (AL) * bfhi(XV.x); \
        acc[2] += (AL) * bflo(XV.y); acc[3] += (AL) * bfhi(XV.y); \
        acc[4] += (AL) * bflo(XV.z); acc[5] += (AL) * bfhi(XV.z); \
        acc[6] += (AL) * bflo(XV.w); acc[7] += (AL) * bfhi(XV.w); \
    }

__global__ __launch_bounds__(256) void k_agg(const __hip_bfloat16* __restrict__ xlb,
                                             const float* __restrict__ als,
                                             const float* __restrict__ ald,
                                             const int* __restrict__ rowptr,
                                             const int* __restrict__ csrc,
                                             const float* __restrict__ bias,
                                             __hip_bfloat16* __restrict__ hb,
                                             const float* __restrict__ w3,
                                             float* __restrict__ xl3, int n) {
    int node = (int)(((size_t)blockIdx.x * blockDim.x + threadIdx.x) >> 6);
    if (node >= n) return;
    int lane = threadIdx.x & 63;
    int beg = rowptr[node];
    int deg = rowptr[node + 1] - beg;

    int h1 = lane & 7, slot = lane >> 3;
    int half = lane >> 5;
    int l5 = lane & 31;
    int h2 = l5 >> 2;
    int ch0 = l5 << 3;
    int sh_alpha = (half << 3) + h2;
    int sh_sidx = (half << 3);
    const __hip_bfloat16* xrow = xlb + ch0;

    float aldv = ald[node * 8 + h1];
    float m = -1e30f, s = 0.f;
    float acc[8] = {};

    // preload chunk 0
    int sb = csrc[beg + min(slot, deg - 1)];
    float alsv = als[sb * 8 + h1];

    for (int base = 0; base < deg; base += 8) {
        int lim = deg - base;
        // issue current-chunk row gathers ASAP (only need sidx)
        int sx0 = __shfl(sb, sh_sidx);
        int sx1 = __shfl(sb, sh_sidx + 16);
        int sx2 = __shfl(sb, sh_sidx + 32);
        int sx3 = __shfl(sb, sh_sidx + 48);
        uint4 xv0 = {}, xv1 = {}, xv2 = {}, xv3 = {};
        if (half + 0 < lim) xv0 = *(const uint4*)(xrow + ((size_t)sx0 << 8));
        if (half + 2 < lim) xv1 = *(const uint4*)(xrow + ((size_t)sx1 << 8));
        if (half + 4 < lim) xv2 = *(const uint4*)(xrow + ((size_t)sx2 << 8));
        if (half + 6 < lim) xv3 = *(const uint4*)(xrow + ((size_t)sx3 << 8));
        // prefetch next chunk's csrc
        int nb = base + 8;
        int sb_n = 0;
        bool more = nb < deg;
        if (more) sb_n = csrc[beg + min(nb + slot, deg - 1)];
        // softmax stats for current chunk (als preloaded last iteration)
        float e = -1e30f;
        if (base + slot < deg) {
            e = alsv + aldv;
            e = e > 0.f ? e : NEG_SLOPE * e;
        }
        float mc = fmaxf(e, __shfl_xor(e, 8));
        mc = fmaxf(mc, __shfl_xor(mc, 16));
        mc = fmaxf(mc, __shfl_xor(mc, 32));
        float mn = fmaxf(m, mc);
        float scale = __expf(m - mn);
        float aval = __expf(e - mn);      // 0 for invalid slots
        float csum = aval + __shfl_xor(aval, 8);
        csum += __shfl_xor(csum, 16);
        csum += __shfl_xor(csum, 32);
        s = s * scale + csum;
        m = mn;
        // prefetch next chunk's als (depends on sb_n)
        float als_n = 0.f;
        if (more) als_n = als[sb_n * 8 + h1];
        // alphas + accumulate
        float sca = __shfl(scale, h2);
        float a0 = __shfl(aval, sh_alpha);
        float a1 = __shfl(aval, sh_alpha + 16);
        float a2 = __shfl(aval, sh_alpha + 32);
        float a3 = __shfl(aval, sh_alpha + 48);
#pragma unroll
        for (int c = 0; c < 8; ++c) acc[c] *= sca;
        if (half + 0 < lim) FMA8(xv0, a0)
        if (half + 2 < lim) FMA8(xv1, a1)
        if (half + 4 < lim) FMA8(xv2, a2)
        if (half + 6 < lim) FMA8(xv3, a3)
        sb = sb_n;
        alsv = als_n;
    }
    // merge the two edge-halves
#pragma unroll
    for (int c = 0; c < 8; ++c) acc[c] += __shfl_xor(acc[c], 32);
    float inv = __shfl(1.f / (s + 1e-16f), h2);
    float o[8];
    float4 bv0 = *reinterpret_cast<const float4*>(bias + ch0);
    float4 bv1 = *reinterpret_cast<const float4*>(bias + ch0 + 4);
    o[0] = acc[0] * inv + bv0.x; o[1] = acc[1] * inv + bv0.y;
    o[2] = acc[2] * inv + bv0.z; o[3] = acc[3] * inv + bv0.w;
    o[4] = acc[4] * inv + bv1.x; o[5] = acc[5] * inv + bv1.y;
    o[6] = acc[6] * inv + bv1.z; o[7] = acc[7] * inv + bv1.w;
#pragma unroll
    for (int c = 0; c < 8; ++c) o[c] = o[c] > 0.f ? o[c] : expm1f(o[c]);

    if (w3) {
        float p = 0.f;
        if (half == 0) {
#pragma unroll
            for (int c = 0; c < 8; ++c) p += o[c] * w3[ch0 + c];
        }
#pragma unroll
        for (int off = 1; off < 64; off <<= 1) p += __shfl_xor(p, off);
        if (lane == 0) xl3[node] = p;
    } else if (half == 0) {
        uint4 ov;
        ov.x = (unsigned)f2bf(o[0]) | ((unsigned)f2bf(o[1]) << 16);
        ov.y = (unsigned)f2bf(o[2]) | ((unsigned)f2bf(o[3]) << 16);
        ov.z = (unsigned)f2bf(o[4]) | ((unsigned)f2bf(o[5]) << 16);
        ov.w = (unsigned)f2bf(o[6]) | ((unsigned)f2bf(o[7]) << 16);
        *(uint4*)(hb + (size_t)node * 256 + ch0) = ov;
    }
}

// ---------------- layer 3 final ----------------

__global__ __launch_bounds__(256) void k_final(const float* __restrict__ xl3,
                                               const int* __restrict__ rowptr,
                                               const int* __restrict__ csrc,
                                               const float* __restrict__ as3,
                                               const float* __restrict__ ad3,
                                               const float* __restrict__ b3,
                                               float* __restrict__ out, int n) {
    int node = (int)(((size_t)blockIdx.x * blockDim.x + threadIdx.x) >> 6);
    if (node >= n) return;
    int lane = threadIdx.x & 63;
    int beg = rowptr[node];
    int deg = rowptr[node + 1] - beg;
    float a_s = as3[0], a_d = ad3[0], bb = b3[0];
    float dterm = a_d * xl3[node];
    float m = -1e30f, s = 0.f, wv = 0.f;
    for (int ee = lane; ee < deg; ee += 64) {
        int sidx = csrc[beg + ee];
        float xs = xl3[sidx];
        float e = a_s * xs + dterm;
        e = e > 0.f ? e : NEG_SLOPE * e;
        float mn = fmaxf(m, e);
        float sc = __expf(m - mn);
        float ex = __expf(e - mn);
        s = s * sc + ex;
        wv = wv * sc + ex * xs;
        m = mn;
    }
#pragma unroll
    for (int off = 1; off < 64; off <<= 1) {
        float m2 = __shfl_xor(m, off);
        float s2 = __shfl_xor(s, off);
        float w2 = __shfl_xor(wv, off);
        float mn = fmaxf(m, m2);
        float sc1 = __expf(m - mn), sc2 = __expf(m2 - mn);
        s = s * sc1 + s2 * sc2;
        wv = wv * sc1 + w2 * sc2;
        m = mn;
    }
    if (lane == 0) out[node] = wv / (s + 1e-16f) + bb;
}

// ---------------- launcher ----------------

extern "C" void kernel_launch(void* const* d_in, const int* in_sizes, int n_in,
                              void* d_out, int out_size, void* d_ws, size_t ws_size,
                              hipStream_t stream) {
    const float* x   = (const float*)d_in[0];
    const int*   ei  = (const int*)d_in[1];
    const float* W0  = (const float*)d_in[2];
    const float* as0 = (const float*)d_in[3];
    const float* ad0 = (const float*)d_in[4];
    const float* b0  = (const float*)d_in[5];
    const float* W1  = (const float*)d_in[6];
    const float* as1 = (const float*)d_in[7];
    const float* ad1 = (const float*)d_in[8];
    const float* b1  = (const float*)d_in[9];
    const float* W2  = (const float*)d_in[10];
    const float* as2 = (const float*)d_in[11];
    const float* ad2 = (const float*)d_in[12];
    const float* b2  = (const float*)d_in[13];
    const float* W3  = (const float*)d_in[14];
    const float* as3 = (const float*)d_in[15];
    const float* ad3 = (const float*)d_in[16];
    const float* b3  = (const float*)d_in[17];

    int N    = in_sizes[0] / 64;   // 30000
    int E    = in_sizes[1] / 2;    // 480000
    int K0   = in_sizes[2] / 256;  // 64
    int Npad = (N + 127) & ~127;   // 30080

    char* ws = (char*)d_ws;
    auto alloc = [&](size_t bytes) {
        char* p = ws;
        ws += (bytes + 255) & ~(size_t)255;
        return p;
    };
    int* rowptr = (int*)alloc((size_t)(N + 1) * 4);
    int* cc     = (int*)alloc((size_t)2 * N * 4);  // cursor | counts
    int* cursor = cc;
    int* counts = cc + N;
    int* csrc   = (int*)alloc((size_t)(E + N) * 4);
    __hip_bfloat16* xb  = (__hip_bfloat16*)alloc((size_t)Npad * K0 * 2);
    __hip_bfloat16* W0t = (__hip_bfloat16*)alloc((size_t)K0 * 256 * 2);
    __hip_bfloat16* W1t = (__hip_bfloat16*)alloc((size_t)256 * 256 * 2);
    __hip_bfloat16* W2t = (__hip_bfloat16*)alloc((size_t)256 * 256 * 2);
    __hip_bfloat16* xlb = (__hip_bfloat16*)alloc((size_t)Npad * 256 * 2);
    __hip_bfloat16* hb  = (__hip_bfloat16*)alloc((size_t)Npad * 256 * 2);
    float* alsall = (float*)alloc((size_t)6 * N * 8 * 4);  // als0 ald0 als1 ald1 als2 ald2
    float* xl3 = (float*)alloc((size_t)N * 4);

    float* als0 = alsall;
    float* ald0 = alsall + (size_t)1 * N * 8;
    float* als1 = alsall + (size_t)2 * N * 8;
    float* ald1 = alsall + (size_t)3 * N * 8;
    float* als2 = alsall + (size_t)4 * N * 8;
    float* ald2 = alsall + (size_t)5 * N * 8;

    hipMemsetAsync(cc, 0, (size_t)2 * N * 4, stream);
    hipMemsetAsync(hb + (size_t)N * 256, 0, (size_t)(Npad - N) * 256 * 2, stream);
    hipMemsetAsync(alsall, 0, (size_t)6 * N * 8 * 4, stream);

    int totA = Npad * K0;
    int totPrep = totA + K0 * 256 + 65536 + 65536;
    k_prep<<<(totPrep + 255) / 256, 256, 0, stream>>>(x, W0, W1, W2, xb, W0t, W1t, W2t,
                                                      N, K0, totA);
    k_hist<<<(E + 255) / 256, 256, 0, stream>>>(ei, E, counts);
    k_scan<<<1, 1024, 0, stream>>>(counts, rowptr, N);
    k_scatter<<<(E + N + 255) / 256, 256, 0, stream>>>(ei, E, N, rowptr, cursor, csrc);

    int nwb = (N + 3) / 4;
    dim3 ggrid(Npad / 128, 2);

    // layer 0
    k_gemm_mfma<<<ggrid, 256, 0, stream>>>(xb, W0t, xlb, K0, 256, as0, ad0, als0, ald0, N);
    k_agg<<<nwb, 256, 0, stream>>>(xlb, als0, ald0, rowptr, csrc, b0, hb, nullptr, nullptr, N);
    // layer 1
    k_gemm_mfma<<<ggrid, 256, 0, stream>>>(hb, W1t, xlb, 256, 256, as1, ad1, als1, ald1, N);
    k_agg<<<nwb, 256, 0, stream>>>(xlb, als1, ald1, rowptr, csrc, b1, hb, nullptr, nullptr, N);
    // layer 2 (+ fused layer-3 matvec)
    k_gemm_mfma<<<ggrid, 256, 0, stream>>>(hb, W2t, xlb, 256, 256, as2, ad2, als2, ald2, N);
    k_agg<<<nwb, 256, 0, stream>>>(xlb, als2, ald2, rowptr, csrc, b2, hb, W3, xl3, N);
    // layer 3
    k_final<<<nwb, 256, 0, stream>>>(xl3, rowptr, csrc, as3, ad3, b3, (float*)d_out, N);
}

// Round 5
// 284.198 us; speedup vs baseline: 1.1970x; 1.1970x over previous
//
#include <hip/hip_runtime.h>
#include <hip/hip_bf16.h>

#define NEG_SLOPE 0.2f

typedef __attribute__((ext_vector_type(8))) short bf16x8;
typedef __attribute__((ext_vector_type(4))) float f32x4;

__device__ __forceinline__ void gload_lds16(const void* g, void* l) {
    __builtin_amdgcn_global_load_lds((const __attribute__((address_space(1))) void*)g,
                                     (__attribute__((address_space(3))) void*)l,
                                     16, 0, 0);
}
__device__ __forceinline__ float bflo(unsigned int u) {
    return __uint_as_float(u << 16);
}
__device__ __forceinline__ float bfhi(unsigned int u) {
    return __uint_as_float(u & 0xffff0000u);
}
__device__ __forceinline__ unsigned short f2bf(float f) {
    __hip_bfloat16 h = __float2bfloat16(f);
    return *reinterpret_cast<unsigned short*>(&h);
}

// ---------------- CSR build ----------------

__global__ void k_hist(const int* __restrict__ ei, int E, int* counts) {
    int i = blockIdx.x * blockDim.x + threadIdx.x;
    if (i < E) atomicAdd(&counts[ei[E + i]], 1);
}

// chunked scan over (counts[i]+1) -> rowptr[0..n]; +1 = self loop
__global__ __launch_bounds__(1024) void k_scan(const int* __restrict__ counts,
                                               int* __restrict__ rowptr, int n) {
    __shared__ int wsum[16];
    __shared__ int wpre[16];
    int t = threadIdx.x;
    int chunk = (n + 1023) >> 10;
    int lo = t * chunk, hi = min(lo + chunk, n);
    if (lo > n) lo = n;
    if (hi < lo) hi = lo;
    int s = 0;
    for (int i = lo; i < hi; ++i) s += counts[i] + 1;
    int lane = t & 63, w = t >> 6;
    int v = s;
#pragma unroll
    for (int off = 1; off < 64; off <<= 1) {
        int u = __shfl_up(v, off);
        if (lane >= off) v += u;
    }
    if (lane == 63) wsum[w] = v;
    __syncthreads();
    if (w == 0 && lane < 16) {
        int x = wsum[lane];
#pragma unroll
        for (int off = 1; off < 16; off <<= 1) {
            int u = __shfl_up(x, off);
            if (lane >= off) x += u;
        }
        wpre[lane] = x - wsum[lane];
    }
    __syncthreads();
    int run = wpre[w] + v - s;
    for (int i = lo; i < hi; ++i) { rowptr[i] = run; run += counts[i] + 1; }
    if (t == 1023) rowptr[n] = run;
}

// self loop at slot rowptr[d]; edges at rowptr[d]+1+cursor
__global__ void k_scatter(const int* __restrict__ ei, int E, int n,
                          const int* __restrict__ rowptr, int* __restrict__ cursor,
                          int* __restrict__ csrc) {
    int i = blockIdx.x * blockDim.x + threadIdx.x;
    int tot = E + n;
    if (i >= tot) return;
    if (i >= E) {
        int d = i - E;
        csrc[rowptr[d]] = d;
    } else {
        int s = ei[i], d = ei[E + i];
        int pos = rowptr[d] + 1 + atomicAdd(&cursor[d], 1);
        csrc[pos] = s;
    }
}

// ---------------- fused conversions: xb pad-cast + 3 weight transposes ----------------

__global__ void k_prep(const float* __restrict__ x, const float* __restrict__ W0,
                       const float* __restrict__ W1, const float* __restrict__ W2,
                       __hip_bfloat16* __restrict__ xb, __hip_bfloat16* __restrict__ W0t,
                       __hip_bfloat16* __restrict__ W1t, __hip_bfloat16* __restrict__ W2t,
                       int N, int K0, int totA) {
    int i = blockIdx.x * blockDim.x + threadIdx.x;
    if (i < totA) {
        int r = i / K0;
        xb[i] = __float2bfloat16(r < N ? x[i] : 0.f);
        return;
    }
    i -= totA;
    if (i < K0 * 256) {
        int c = i / K0, k = i - c * K0;
        W0t[i] = __float2bfloat16(W0[k * 256 + c]);
        return;
    }
    i -= K0 * 256;
    if (i < 65536) {
        int c = i >> 8, k = i & 255;
        W1t[i] = __float2bfloat16(W1[k * 256 + c]);
        return;
    }
    i -= 65536;
    if (i < 65536) {
        int c = i >> 8, k = i & 255;
        W2t[i] = __float2bfloat16(W2[k * 256 + c]);
    }
}

// ---------------- bf16 MFMA GEMM: C[Mpad,256] = A[Mpad,K] @ Bt[256,K]^T ----------------

__global__ __launch_bounds__(256) void k_gemm_mfma(
    const __hip_bfloat16* __restrict__ A,   // [Mpad][K]
    const __hip_bfloat16* __restrict__ Bt,  // [NC][K]
    __hip_bfloat16* __restrict__ Cb,        // [Mpad][NC]
    int K, int NC)
{
    __shared__ __hip_bfloat16 As[128 * 32];
    __shared__ __hip_bfloat16 Bs[128 * 32];
    int tid = threadIdx.x;
    int lane = tid & 63, w = tid >> 6;
    int wm = w >> 1, wn = w & 1;
    int rr = lane & 15, kg = lane >> 4;
    int bm = blockIdx.x * 128, bn = blockIdx.y * 128;

    f32x4 acc[4][4] = {};

    for (int k0 = 0; k0 < K; k0 += 32) {
#pragma unroll
        for (int s = 0; s < 2; ++s) {
            int c = tid + s * 256;
            int r = c >> 2, sl = c & 3;
            int ksrc = k0 + 8 * (sl ^ ((r >> 1) & 3));
            char* dstA = ((char*)As) + s * 4096 + w * 1024;
            char* dstB = ((char*)Bs) + s * 4096 + w * 1024;
            gload_lds16(A + (size_t)(bm + r) * K + ksrc, dstA);
            gload_lds16(Bt + (size_t)(bn + r) * K + ksrc, dstB);
        }
        __syncthreads();
        bf16x8 af[4], bfr[4];
#pragma unroll
        for (int i = 0; i < 4; ++i) {
            int row = wm * 64 + i * 16 + rr;
            af[i] = *(const bf16x8*)((const char*)As + row * 64 + ((kg ^ ((row >> 1) & 3)) << 4));
        }
#pragma unroll
        for (int j = 0; j < 4; ++j) {
            int col = wn * 64 + j * 16 + rr;
            bfr[j] = *(const bf16x8*)((const char*)Bs + col * 64 + ((kg ^ ((col >> 1) & 3)) << 4));
        }
#pragma unroll
        for (int i = 0; i < 4; ++i)
#pragma unroll
            for (int j = 0; j < 4; ++j)
                acc[i][j] = __builtin_amdgcn_mfma_f32_16x16x32_bf16(af[i], bfr[j], acc[i][j], 0, 0, 0);
        __syncthreads();
    }
#pragma unroll
    for (int i = 0; i < 4; ++i) {
#pragma unroll
        for (int j = 0; j < 4; ++j) {
            int col = bn + wn * 64 + j * 16 + rr;
#pragma unroll
            for (int q = 0; q < 4; ++q) {
                int row = bm + wm * 64 + i * 16 + kg * 4 + q;
                Cb[(size_t)row * NC + col] = __float2bfloat16(acc[i][j][q]);
            }
        }
    }
}

// ---------------- attention coefficients from bf16 xl ----------------

__global__ __launch_bounds__(256) void k_attn(const __hip_bfloat16* __restrict__ xlb,
                                              const float* __restrict__ as_,
                                              const float* __restrict__ ad_,
                                              float* __restrict__ als,
                                              float* __restrict__ ald, int n) {
    int node = (int)(((size_t)blockIdx.x * blockDim.x + threadIdx.x) >> 6);
    if (node >= n) return;
    int lane = threadIdx.x & 63;
    uint2 xv = *(const uint2*)(xlb + (size_t)node * 256 + (lane << 2));
    float x0 = bflo(xv.x), x1 = bfhi(xv.x), x2 = bflo(xv.y), x3 = bfhi(xv.y);
    float4 sv = *reinterpret_cast<const float4*>(as_ + (lane << 2));
    float4 dv = *reinterpret_cast<const float4*>(ad_ + (lane << 2));
    float ps = x0 * sv.x + x1 * sv.y + x2 * sv.z + x3 * sv.w;
    float pd = x0 * dv.x + x1 * dv.y + x2 * dv.z + x3 * dv.w;
#pragma unroll
    for (int off = 1; off < 8; off <<= 1) {
        ps += __shfl_xor(ps, off);
        pd += __shfl_xor(pd, off);
    }
    if ((lane & 7) == 0) {
        als[node * 8 + (lane >> 3)] = ps;
        ald[node * 8 + (lane >> 3)] = pd;
    }
}

// ---------------- pipelined flash aggregation, 16 edges/chunk + ELU (+ matvec) ----------
// stats: lane = 8*slot + head; lane handles edges base+slot and base+slot+8
// gather: half = lane>>5; lane handles 8 channels ch0=(lane&31)*8 of edges half+2t

#define FMA8(XV, AL)                                              \
    {                                                             \
        acc[0] += (AL) * bflo(XV.x); acc[1] += (AL) * bfhi(XV.x); \
        acc[2] += (AL) * bflo(XV.y); acc[3] += (AL) * bfhi(XV.y); \
        acc[4] += (AL) * bflo(XV.z); acc[5] += (AL) * bfhi(XV.z); \
        acc[6] += (AL) * bflo(XV.w); acc[7] += (AL) * bfhi(XV.w); \
    }

__global__ __launch_bounds__(256) void k_agg(const __hip_bfloat16* __restrict__ xlb,
                                             const float* __restrict__ als,
                                             const float* __restrict__ ald,
                                             const int* __restrict__ rowptr,
                                             const int* __restrict__ csrc,
                                             const float* __restrict__ bias,
                                             __hip_bfloat16* __restrict__ hb,
                                             const float* __restrict__ w3,
                                             float* __restrict__ xl3, int n) {
    int node = (int)(((size_t)blockIdx.x * blockDim.x + threadIdx.x) >> 6);
    if (node >= n) return;
    int lane = threadIdx.x & 63;
    int beg = rowptr[node];
    int deg = rowptr[node + 1] - beg;

    int h1 = lane & 7, slot = lane >> 3;
    int half = lane >> 5;
    int l5 = lane & 31;
    int h2 = l5 >> 2;
    int ch0 = l5 << 3;
    const __hip_bfloat16* xrow = xlb + ch0;

    float aldv = ald[node * 8 + h1];
    float m = -1e30f, s = 0.f;
    float acc[8] = {};

    // preload chunk 0 csrc + als
    int sb0 = csrc[beg + min(slot, deg - 1)];
    int sb1 = csrc[beg + min(slot + 8, deg - 1)];
    float av_s0 = als[sb0 * 8 + h1];
    float av_s1 = als[sb1 * 8 + h1];

    for (int base = 0; base < deg; base += 16) {
        int lim = deg - base;
        // broadcast source indices, issue up to 8 row gathers immediately
        int sxa = __shfl(sb0, (half + 0) << 3);
        int sxb = __shfl(sb0, (half + 2) << 3);
        int sxc = __shfl(sb0, (half + 4) << 3);
        int sxd = __shfl(sb0, (half + 6) << 3);
        int sxe = __shfl(sb1, (half + 0) << 3);
        int sxf = __shfl(sb1, (half + 2) << 3);
        int sxg = __shfl(sb1, (half + 4) << 3);
        int sxh = __shfl(sb1, (half + 6) << 3);
        uint4 xva = {}, xvb = {}, xvc = {}, xvd = {};
        uint4 xve = {}, xvf = {}, xvg = {}, xvh = {};
        if (half + 0  < lim) xva = *(const uint4*)(xrow + ((size_t)sxa << 8));
        if (half + 2  < lim) xvb = *(const uint4*)(xrow + ((size_t)sxb << 8));
        if (half + 4  < lim) xvc = *(const uint4*)(xrow + ((size_t)sxc << 8));
        if (half + 6  < lim) xvd = *(const uint4*)(xrow + ((size_t)sxd << 8));
        if (half + 8  < lim) xve = *(const uint4*)(xrow + ((size_t)sxe << 8));
        if (half + 10 < lim) xvf = *(const uint4*)(xrow + ((size_t)sxf << 8));
        if (half + 12 < lim) xvg = *(const uint4*)(xrow + ((size_t)sxg << 8));
        if (half + 14 < lim) xvh = *(const uint4*)(xrow + ((size_t)sxh << 8));
        // prefetch next chunk's csrc
        int nb = base + 16;
        bool more = nb < deg;
        int sb0n = 0, sb1n = 0;
        if (more) {
            sb0n = csrc[beg + min(nb + slot, deg - 1)];
            sb1n = csrc[beg + min(nb + slot + 8, deg - 1)];
        }
        // softmax stats (als preloaded)
        float e0 = -1e30f, e1 = -1e30f;
        if (slot < lim) { e0 = av_s0 + aldv; e0 = e0 > 0.f ? e0 : NEG_SLOPE * e0; }
        if (slot + 8 < lim) { e1 = av_s1 + aldv; e1 = e1 > 0.f ? e1 : NEG_SLOPE * e1; }
        float mc = fmaxf(e0, e1);
        mc = fmaxf(mc, __shfl_xor(mc, 8));
        mc = fmaxf(mc, __shfl_xor(mc, 16));
        mc = fmaxf(mc, __shfl_xor(mc, 32));
        float mn = fmaxf(m, mc);
        float scale = __expf(m - mn);
        float a0 = __expf(e0 - mn);
        float a1 = __expf(e1 - mn);
        float csum = a0 + a1;
        csum += __shfl_xor(csum, 8);
        csum += __shfl_xor(csum, 16);
        csum += __shfl_xor(csum, 32);
        s = s * scale + csum;
        m = mn;
        // prefetch next chunk's als
        float als0n = 0.f, als1n = 0.f;
        if (more) {
            als0n = als[sb0n * 8 + h1];
            als1n = als[sb1n * 8 + h1];
        }
        // rescale + accumulate
        float sca = __shfl(scale, h2);
#pragma unroll
        for (int c = 0; c < 8; ++c) acc[c] *= sca;
        float al;
        al = __shfl(a0, ((half + 0) << 3) + h2); if (half + 0  < lim) FMA8(xva, al)
        al = __shfl(a0, ((half + 2) << 3) + h2); if (half + 2  < lim) FMA8(xvb, al)
        al = __shfl(a0, ((half + 4) << 3) + h2); if (half + 4  < lim) FMA8(xvc, al)
        al = __shfl(a0, ((half + 6) << 3) + h2); if (half + 6  < lim) FMA8(xvd, al)
        al = __shfl(a1, ((half + 0) << 3) + h2); if (half + 8  < lim) FMA8(xve, al)
        al = __shfl(a1, ((half + 2) << 3) + h2); if (half + 10 < lim) FMA8(xvf, al)
        al = __shfl(a1, ((half + 4) << 3) + h2); if (half + 12 < lim) FMA8(xvg, al)
        al = __shfl(a1, ((half + 6) << 3) + h2); if (half + 14 < lim) FMA8(xvh, al)
        sb0 = sb0n; sb1 = sb1n;
        av_s0 = als0n; av_s1 = als1n;
    }
    // merge the two edge-halves
#pragma unroll
    for (int c = 0; c < 8; ++c) acc[c] += __shfl_xor(acc[c], 32);
    float inv = __shfl(1.f / (s + 1e-16f), h2);
    float o[8];
    float4 bv0 = *reinterpret_cast<const float4*>(bias + ch0);
    float4 bv1 = *reinterpret_cast<const float4*>(bias + ch0 + 4);
    o[0] = acc[0] * inv + bv0.x; o[1] = acc[1] * inv + bv0.y;
    o[2] = acc[2] * inv + bv0.z; o[3] = acc[3] * inv + bv0.w;
    o[4] = acc[4] * inv + bv1.x; o[5] = acc[5] * inv + bv1.y;
    o[6] = acc[6] * inv + bv1.z; o[7] = acc[7] * inv + bv1.w;
#pragma unroll
    for (int c = 0; c < 8; ++c) o[c] = o[c] > 0.f ? o[c] : expm1f(o[c]);

    if (w3) {
        float p = 0.f;
        if (half == 0) {
#pragma unroll
            for (int c = 0; c < 8; ++c) p += o[c] * w3[ch0 + c];
        }
#pragma unroll
        for (int off = 1; off < 64; off <<= 1) p += __shfl_xor(p, off);
        if (lane == 0) xl3[node] = p;
    } else if (half == 0) {
        uint4 ov;
        ov.x = (unsigned)f2bf(o[0]) | ((unsigned)f2bf(o[1]) << 16);
        ov.y = (unsigned)f2bf(o[2]) | ((unsigned)f2bf(o[3]) << 16);
        ov.z = (unsigned)f2bf(o[4]) | ((unsigned)f2bf(o[5]) << 16);
        ov.w = (unsigned)f2bf(o[6]) | ((unsigned)f2bf(o[7]) << 16);
        *(uint4*)(hb + (size_t)node * 256 + ch0) = ov;
    }
}

// ---------------- layer 3 final ----------------

__global__ __launch_bounds__(256) void k_final(const float* __restrict__ xl3,
                                               const int* __restrict__ rowptr,
                                               const int* __restrict__ csrc,
                                               const float* __restrict__ as3,
                                               const float* __restrict__ ad3,
                                               const float* __restrict__ b3,
                                               float* __restrict__ out, int n) {
    int node = (int)(((size_t)blockIdx.x * blockDim.x + threadIdx.x) >> 6);
    if (node >= n) return;
    int lane = threadIdx.x & 63;
    int beg = rowptr[node];
    int deg = rowptr[node + 1] - beg;
    float a_s = as3[0], a_d = ad3[0], bb = b3[0];
    float dterm = a_d * xl3[node];
    float m = -1e30f, s = 0.f, wv = 0.f;
    for (int ee = lane; ee < deg; ee += 64) {
        int sidx = csrc[beg + ee];
        float xs = xl3[sidx];
        float e = a_s * xs + dterm;
        e = e > 0.f ? e : NEG_SLOPE * e;
        float mn = fmaxf(m, e);
        float sc = __expf(m - mn);
        float ex = __expf(e - mn);
        s = s * sc + ex;
        wv = wv * sc + ex * xs;
        m = mn;
    }
#pragma unroll
    for (int off = 1; off < 64; off <<= 1) {
        float m2 = __shfl_xor(m, off);
        float s2 = __shfl_xor(s, off);
        float w2 = __shfl_xor(wv, off);
        float mn = fmaxf(m, m2);
        float sc1 = __expf(m - mn), sc2 = __expf(m2 - mn);
        s = s * sc1 + s2 * sc2;
        wv = wv * sc1 + w2 * sc2;
        m = mn;
    }
    if (lane == 0) out[node] = wv / (s + 1e-16f) + bb;
}

// ---------------- launcher ----------------

extern "C" void kernel_launch(void* const* d_in, const int* in_sizes, int n_in,
                              void* d_out, int out_size, void* d_ws, size_t ws_size,
                              hipStream_t stream) {
    const float* x   = (const float*)d_in[0];
    const int*   ei  = (const int*)d_in[1];
    const float* W0  = (const float*)d_in[2];
    const float* as0 = (const float*)d_in[3];
    const float* ad0 = (const float*)d_in[4];
    const float* b0  = (const float*)d_in[5];
    const float* W1  = (const float*)d_in[6];
    const float* as1 = (const float*)d_in[7];
    const float* ad1 = (const float*)d_in[8];
    const float* b1  = (const float*)d_in[9];
    const float* W2  = (const float*)d_in[10];
    const float* as2 = (const float*)d_in[11];
    const float* ad2 = (const float*)d_in[12];
    const float* b2  = (const float*)d_in[13];
    const float* W3  = (const float*)d_in[14];
    const float* as3 = (const float*)d_in[15];
    const float* ad3 = (const float*)d_in[16];
    const float* b3  = (const float*)d_in[17];

    int N    = in_sizes[0] / 64;   // 30000
    int E    = in_sizes[1] / 2;    // 480000
    int K0   = in_sizes[2] / 256;  // 64
    int Npad = (N + 127) & ~127;   // 30080

    char* ws = (char*)d_ws;
    auto alloc = [&](size_t bytes) {
        char* p = ws;
        ws += (bytes + 255) & ~(size_t)255;
        return p;
    };
    int* rowptr = (int*)alloc((size_t)(N + 1) * 4);
    int* cc     = (int*)alloc((size_t)2 * N * 4);  // cursor | counts
    int* cursor = cc;
    int* counts = cc + N;
    int* csrc   = (int*)alloc((size_t)(E + N) * 4);
    __hip_bfloat16* xb  = (__hip_bfloat16*)alloc((size_t)Npad * K0 * 2);
    __hip_bfloat16* W0t = (__hip_bfloat16*)alloc((size_t)K0 * 256 * 2);
    __hip_bfloat16* W1t = (__hip_bfloat16*)alloc((size_t)256 * 256 * 2);
    __hip_bfloat16* W2t = (__hip_bfloat16*)alloc((size_t)256 * 256 * 2);
    __hip_bfloat16* xlb = (__hip_bfloat16*)alloc((size_t)Npad * 256 * 2);
    __hip_bfloat16* hb  = (__hip_bfloat16*)alloc((size_t)Npad * 256 * 2);
    float* als = (float*)alloc((size_t)N * 8 * 4);
    float* ald = (float*)alloc((size_t)N * 8 * 4);
    float* xl3 = (float*)alloc((size_t)N * 4);

    hipMemsetAsync(cc, 0, (size_t)2 * N * 4, stream);
    hipMemsetAsync(hb + (size_t)N * 256, 0, (size_t)(Npad - N) * 256 * 2, stream);

    int totA = Npad * K0;
    int totPrep = totA + K0 * 256 + 65536 + 65536;
    k_prep<<<(totPrep + 255) / 256, 256, 0, stream>>>(x, W0, W1, W2, xb, W0t, W1t, W2t,
                                                      N, K0, totA);
    k_hist<<<(E + 255) / 256, 256, 0, stream>>>(ei, E, counts);
    k_scan<<<1, 1024, 0, stream>>>(counts, rowptr, N);
    k_scatter<<<(E + N + 255) / 256, 256, 0, stream>>>(ei, E, N, rowptr, cursor, csrc);

    int nwb = (N + 3) / 4;
    dim3 ggrid(Npad / 128, 2);

    // layer 0
    k_gemm_mfma<<<ggrid, 256, 0, stream>>>(xb, W0t, xlb, K0, 256);
    k_attn<<<nwb, 256, 0, stream>>>(xlb, as0, ad0, als, ald, N);
    k_agg<<<nwb, 256, 0, stream>>>(xlb, als, ald, rowptr, csrc, b0, hb, nullptr, nullptr, N);
    // layer 1
    k_gemm_mfma<<<ggrid, 256, 0, stream>>>(hb, W1t, xlb, 256, 256);
    k_attn<<<nwb, 256, 0, stream>>>(xlb, as1, ad1, als, ald, N);
    k_agg<<<nwb, 256, 0, stream>>>(xlb, als, ald, rowptr, csrc, b1, hb, nullptr, nullptr, N);
    // layer 2 (+ fused layer-3 matvec)
    k_gemm_mfma<<<ggrid, 256, 0, stream>>>(hb, W2t, xlb, 256, 256);
    k_attn<<<nwb, 256, 0, stream>>>(xlb, as2, ad2, als, ald, N);
    k_agg<<<nwb, 256, 0, stream>>>(xlb, als, ald, rowptr, csrc, b2, hb, W3, xl3, N);
    // layer 3
    k_final<<<nwb, 256, 0, stream>>>(xl3, rowptr, csrc, as3, ad3, b3, (float*)d_out, N);
}